// Round 6
// baseline (43193.665 us; speedup 1.0000x reference)
//
#include <hip/hip_runtime.h>

#define L 64
#define TLEN 200000
#define CH 528                        // divisible by 8; checkpoint cadence
#define NCH 379                       // ceil(200000/528); 378*528 = 199584
#define LASTLEN (TLEN - (NCH - 1) * CH)   // 416 (divisible by 8)
#define NEGV -10000.0f
#define STARTT 62
#define STOPT 63

// workspace layout (bytes) — total 123052 < 126940 proven available
#define CKPT_OFF 0                          // float[(NCH+1)*L]  = 97280 B
#define M_OFF ((NCH + 1) * L * 4)           // uchar[NCH*L]      = 24256 B
#define ETAG_OFF (M_OFF + NCH * L)          // int[NCH]          = 1516 B

typedef float f32x4 __attribute__((ext_vector_type(4)));

// Per-step barrier WITHOUT lgkmcnt drain — validated rounds 3-5 (absmax 0):
// pre-barrier LDS ops are serviced before post-barrier ops reach the pipe.
#define FAST_BARRIER() __asm__ volatile("s_barrier" ::: "memory")
#define STEP_BARRIER() __asm__ volatile("" ::: "memory")

// force v_max3_f32 (3-input max, 1 instruction); max is order-invariant over
// finite floats so every tree below is bit-identical to pairwise fmax.
__device__ __forceinline__ float max3f(float a, float b, float c) {
    float r;
    __asm__("v_max3_f32 %0, %1, %2, %3" : "=v"(r) : "v"(a), "v"(b), "v"(c));
    return r;
}

// DPP row_ror:k — rotate within each 16-lane row: dst lane i = src lane (i-k)&15.
// (Direction per AMD DPP prefix-scan idiom: row_shr:n feeds lane i from lane i-n.)
// ctrl = 0x120 | k. All args after src must be literals -> explicit lines below.
#define DPPROR(vi, ctrl) \
    __int_as_float(__builtin_amdgcn_update_dpp(vi, vi, ctrl, 0xf, 0xf, false))

// ---------------------------------------------------------------------------
// Pass 1: exact sequential forward recurrence (the critical path).
// 4 waves (256 threads). Wave w owns prev-slice [16w, 16w+16).
// Round-5 lesson: v_readlane broadcast costs ~10cy/op on the dependent chain
// (twice measured); R3's LDS path costs TWO ~130cy LDS latencies. This
// version keeps the broadcast in the VALU domain via DPP row rotation:
//   state: lane l (r=l&15) holds vsrc = v_t[16w+r] (replicated in 4 row-groups).
//   (1) 16 independent v_add with DPP row_ror:k on src0: c_k = v[16w+((r-k)&15)]
//       + tq[k], where tq[k] = T[l][16w+((r-k)&15)] pre-rotated per lane at
//       init. k=0..15 covers the whole slice. Pure VALU, ~2cy each.
//   (2) 8-op max3 tree -> partial_w[l] ; + feat[t][l] (RN monotone => exact).
//   (3) ONE plain ds_write_b32 pm[l][w ^ ((l>>3)&3)] (XOR comp spread: lanes
//       l, l+8, l+16, l+24 hit distinct banks; 2-way overall = free).
//   (4) no-drain barrier; ONE ds_read_b128 pm[16w+r][0..3] (16 addrs x 4-lane
//       broadcast, 2-way banks = free) + max3/fmax combine -> v_{t+1}[16w+r].
// Chain: ~130 (read) + ~55 (VALU) + barrier ~ 235 cy/step vs R3's 352 (which
// paid read AND atomic-service latencies serially).
// Bit-exactness: each score is one RN(v[p]+T[n][p]); maxes order-invariant;
// feat added once pre-max-combine (monotone RN identity, validated R3-R5).
// Checkpoints match the reference bit-for-bit; replay kernels unchanged.
// ---------------------------------------------------------------------------
__global__ __launch_bounds__(256, 1) void k_forward(const float* __restrict__ feats,
                                                    const float* __restrict__ trans,
                                                    float* __restrict__ ckpt) {
    const int tid = threadIdx.x;
    const int l = tid & 63;   // lane = dest-tag for the partial compute
    const int w = tid >> 6;   // wave id = prev-slice
    const int r = l & 15;     // slice element this lane combines/carries
    const int wc = w ^ ((l >> 3) & 3);   // write component (bank de-conflict)
    const int rp = 16 * w + r;           // prev-tag carried by this lane

    // per-lane ROTATED T row slice: tq[k] = T[l][16w + ((r-k)&15)], 16 scalars
    float t0 = trans[l * L + 16 * w + ((r - 0) & 15)];
    float t1 = trans[l * L + 16 * w + ((r - 1) & 15)];
    float t2 = trans[l * L + 16 * w + ((r - 2) & 15)];
    float t3 = trans[l * L + 16 * w + ((r - 3) & 15)];
    float t4 = trans[l * L + 16 * w + ((r - 4) & 15)];
    float t5 = trans[l * L + 16 * w + ((r - 5) & 15)];
    float t6 = trans[l * L + 16 * w + ((r - 6) & 15)];
    float t7 = trans[l * L + 16 * w + ((r - 7) & 15)];
    float t8 = trans[l * L + 16 * w + ((r - 8) & 15)];
    float t9 = trans[l * L + 16 * w + ((r - 9) & 15)];
    float t10 = trans[l * L + 16 * w + ((r - 10) & 15)];
    float t11 = trans[l * L + 16 * w + ((r - 11) & 15)];
    float t12 = trans[l * L + 16 * w + ((r - 12) & 15)];
    float t13 = trans[l * L + 16 * w + ((r - 13) & 15)];
    float t14 = trans[l * L + 16 * w + ((r - 14) & 15)];
    float t15 = trans[l * L + 16 * w + ((r - 15) & 15)];
    // pin: 16 scalars (R0 proved 16 floats/lane allocate; R1's failure was 64)
    __asm__ volatile(""
                     : "+v"(t0), "+v"(t1), "+v"(t2), "+v"(t3), "+v"(t4),
                       "+v"(t5), "+v"(t6), "+v"(t7), "+v"(t8), "+v"(t9),
                       "+v"(t10), "+v"(t11), "+v"(t12), "+v"(t13), "+v"(t14),
                       "+v"(t15));

    // pm[buf][dest-tag][component]; write 2-way, read b128 2-way (both free)
    __shared__ __align__(16) float pm[2][L][4];

    // v_{-1}[rp] in-register
    float vsrc = (rp == STARTT) ? 0.0f : NEGV;

    // feat prefetch: feats[t][l] (dest-tag indexed, coalesced)
    float fc[8];
#pragma unroll
    for (int j = 0; j < 8; ++j) fc[j] = feats[j * L + l];

    int nextck = 0, cidx = 0;

#define FWD_STEP(BUF, FEAT)                                                    \
    do {                                                                       \
        const int vi = __float_as_int(vsrc);                                   \
        const float c0 = vsrc + t0;                                            \
        const float c1 = DPPROR(vi, 0x121) + t1;                               \
        const float c2 = DPPROR(vi, 0x122) + t2;                               \
        const float c3 = DPPROR(vi, 0x123) + t3;                               \
        const float c4 = DPPROR(vi, 0x124) + t4;                               \
        const float c5 = DPPROR(vi, 0x125) + t5;                               \
        const float c6 = DPPROR(vi, 0x126) + t6;                               \
        const float c7 = DPPROR(vi, 0x127) + t7;                               \
        const float c8 = DPPROR(vi, 0x128) + t8;                               \
        const float c9 = DPPROR(vi, 0x129) + t9;                               \
        const float c10 = DPPROR(vi, 0x12A) + t10;                             \
        const float c11 = DPPROR(vi, 0x12B) + t11;                             \
        const float c12 = DPPROR(vi, 0x12C) + t12;                             \
        const float c13 = DPPROR(vi, 0x12D) + t13;                             \
        const float c14 = DPPROR(vi, 0x12E) + t14;                             \
        const float c15 = DPPROR(vi, 0x12F) + t15;                             \
        const float a0 = max3f(c0, c1, c2);                                    \
        const float a1 = max3f(c3, c4, c5);                                    \
        const float a2 = max3f(c6, c7, c8);                                    \
        const float a3 = max3f(c9, c10, c11);                                  \
        const float a4 = max3f(c12, c13, c14);                                 \
        const float pmv =                                                      \
            fmaxf(max3f(a0, a1, a2), max3f(a3, a4, c15)) + (FEAT);             \
        pm[BUF][l][wc] = pmv;                                                  \
        FAST_BARRIER();                                                        \
        const f32x4 pq = *reinterpret_cast<const f32x4*>(&pm[BUF][rp][0]);     \
        vsrc = fmaxf(max3f(pq.x, pq.y, pq.z), pq.w);                           \
    } while (0)

    for (int tb = 0; tb < TLEN; tb += 8) {
        if (tb == nextck) {
            // vsrc holds v_{tb-1}[16w+r]; lanes l<16 (r=l) cover the slice
            if (l < 16) ckpt[cidx * L + 16 * w + l] = vsrc;
            nextck += CH;
            ++cidx;
        }
        float fn_[8];
        const bool more = (tb + 8) < TLEN;
        if (more) {
#pragma unroll
            for (int j = 0; j < 8; ++j) fn_[j] = feats[(tb + 8 + j) * L + l];
        }
        FWD_STEP(0, fc[0]);
        FWD_STEP(1, fc[1]);
        FWD_STEP(0, fc[2]);
        FWD_STEP(1, fc[3]);
        FWD_STEP(0, fc[4]);
        FWD_STEP(1, fc[5]);
        FWD_STEP(0, fc[6]);
        FWD_STEP(1, fc[7]);
        if (more) {
#pragma unroll
            for (int j = 0; j < 8; ++j) fc[j] = fn_[j];
        }
    }
    // vsrc = v_{199999}[16w+r]
    if (l < 16) ckpt[NCH * L + 16 * w + l] = vsrc;
#undef FWD_STEP
}

// ---------------------------------------------------------------------------
// helpers for the replay kernels (off the critical path, ~0.8 ms total)
// ---------------------------------------------------------------------------
__device__ __forceinline__ void load_trow(const float* __restrict__ trans, int n, float* trow) {
#pragma unroll
    for (int i = 0; i < 16; ++i) {
        const f32x4 q = reinterpret_cast<const f32x4*>(trans)[n * 16 + i];
        trow[4 * i + 0] = q.x;
        trow[4 * i + 1] = q.y;
        trow[4 * i + 2] = q.z;
        trow[4 * i + 3] = q.w;
    }
}

// Bit-exact chunk replay from checkpoint; records backpointers into LDS.
// Single wave per block; in-order DS pipe makes ds_write->ds_read safe with
// only a compiler barrier. Argmax is an in-order strictly-greater scan =>
// first-max, matching jnp.argmax; v matches k_forward bit-for-bit (max is
// order-invariant, +feat monotone-exact).
__device__ __forceinline__ void replay_chunk(const float* __restrict__ feats,
                                             const float* __restrict__ ckpt,
                                             const float* trow, float* vsh,
                                             unsigned char* bpl, int c, int len, int n) {
    float vreg = ckpt[c * L + n];
    vsh[n] = vreg;
    STEP_BARRIER();
    const int base = c * CH;

    float fc[8];
#pragma unroll
    for (int j = 0; j < 8; ++j) fc[j] = feats[(base + j) * L + n];

    for (int sb = 0; sb < len; sb += 8) {
        float fn_[8];
        const bool more = (sb + 8) < len;
        if (more) {
#pragma unroll
            for (int j = 0; j < 8; ++j) fn_[j] = feats[(base + sb + 8 + j) * L + n];
        }
#pragma unroll
        for (int j = 0; j < 8; ++j) {
            float mc[4];
            int ic[4];
#pragma unroll
            for (int g = 0; g < 4; ++g) {
                float m = -INFINITY;
                int idx = g * 16;
#pragma unroll
                for (int r = 0; r < 4; ++r) {
                    const int pb = g * 16 + r * 4;
                    const f32x4 vv = *reinterpret_cast<const f32x4*>(vsh + pb);
                    const float a = vv.x + trow[pb + 0];
                    const float b = vv.y + trow[pb + 1];
                    const float cc = vv.z + trow[pb + 2];
                    const float d = vv.w + trow[pb + 3];
                    if (a > m)  { m = a;  idx = pb + 0; }
                    if (b > m)  { m = b;  idx = pb + 1; }
                    if (cc > m) { m = cc; idx = pb + 2; }
                    if (d > m)  { m = d;  idx = pb + 3; }
                }
                mc[g] = m;
                ic[g] = idx;
            }
            float m = mc[0];
            int idx = ic[0];
            if (mc[1] > m) { m = mc[1]; idx = ic[1]; }
            if (mc[2] > m) { m = mc[2]; idx = ic[2]; }
            if (mc[3] > m) { m = mc[3]; idx = ic[3]; }

            vreg = m + fc[j];
            bpl[(sb + j) * L + n] = (unsigned char)idx;
            vsh[n] = vreg;
            STEP_BARRIER();
        }
        if (more) {
#pragma unroll
            for (int j = 0; j < 8; ++j) fc[j] = fn_[j];
        }
    }
}

// ---------------------------------------------------------------------------
// Pass 2: per-chunk bit-exact replay -> backpointers -> 64-entry chunk map.
// M[c*64+e] = tag at (c*CH - 1) given tag e at the last step of chunk c.
// ---------------------------------------------------------------------------
__global__ __launch_bounds__(64, 1) void k_maps(const float* __restrict__ feats,
                                                const float* __restrict__ trans,
                                                const float* __restrict__ ckpt,
                                                unsigned char* __restrict__ M) {
    const int c = blockIdx.x;
    const int n = threadIdx.x;
    const int len = (c == NCH - 1) ? LASTLEN : CH;

    __shared__ __align__(16) float vsh[L];
    __shared__ unsigned char bpl[CH * L];

    float trow[L];
    load_trow(trans, n, trow);
    replay_chunk(feats, ckpt, trow, vsh, bpl, c, len, n);
    __syncthreads();

    int tag = n;
    for (int s = len - 1; s >= 0; --s) tag = bpl[s * L + tag];
    M[c * L + n] = (unsigned char)tag;
}

// ---------------------------------------------------------------------------
// Pass 3: terminal argmax (bit-exact score) + back-to-front map composition.
// ---------------------------------------------------------------------------
__global__ __launch_bounds__(64, 1) void k_stitch(const float* __restrict__ trans,
                                                  const float* __restrict__ ckpt,
                                                  const unsigned char* __restrict__ M,
                                                  int* __restrict__ etag,
                                                  float* __restrict__ out) {
    const int n = threadIdx.x;
    __shared__ float tsh[L];
    __shared__ int bsh;
    __shared__ __align__(16) unsigned char msh[NCH * L];

    tsh[n] = ckpt[NCH * L + n] + trans[STOPT * L + n];  // terminal[n]
    __syncthreads();
    if (n == 0) {
        float m = tsh[0];
        int b = 0;
        for (int p = 1; p < L; ++p)
            if (tsh[p] > m) { m = tsh[p]; b = p; }  // first-max, like jnp.argmax
        out[0] = m;   // path_score, bit-exact
        bsh = b;
    }
    __syncthreads();

    for (int i = n; i < (NCH * L) / 4; i += L)
        reinterpret_cast<int*>(msh)[i] = reinterpret_cast<const int*>(M)[i];
    __syncthreads();

    if (n == 0) {
        int carry = bsh;  // tag at t = T-1 = end of chunk NCH-1
        for (int c = NCH - 1; c >= 1; --c) {
            etag[c] = carry;
            carry = msh[c * L + carry];
        }
        etag[0] = carry;
    }
}

// ---------------------------------------------------------------------------
// Pass 4: per-chunk replay again, walk backwards from etag[c], emit path.
// Path written as float32 (harness reads the concatenated output as float).
// ---------------------------------------------------------------------------
__global__ __launch_bounds__(64, 1) void k_emit(const float* __restrict__ feats,
                                                const float* __restrict__ trans,
                                                const float* __restrict__ ckpt,
                                                const int* __restrict__ etag,
                                                float* __restrict__ out) {
    const int c = blockIdx.x;
    const int n = threadIdx.x;
    const int len = (c == NCH - 1) ? LASTLEN : CH;

    __shared__ __align__(16) float vsh[L];
    __shared__ unsigned char bpl[CH * L];
    __shared__ unsigned char plc[CH];

    float trow[L];
    load_trow(trans, n, trow);
    replay_chunk(feats, ckpt, trow, vsh, bpl, c, len, n);
    __syncthreads();

    int tag = etag[c];  // uniform; bpl reads below broadcast (same address)
    for (int s = len - 1; s >= 0; --s) {
        if (n == 0) plc[s] = (unsigned char)tag;
        tag = bpl[s * L + tag];
    }
    __syncthreads();

    for (int i = n; i < len; i += L)
        out[1 + c * CH + i] = (float)plc[i];
}

// ---------------------------------------------------------------------------
extern "C" void kernel_launch(void* const* d_in, const int* in_sizes, int n_in,
                              void* d_out, int out_size, void* d_ws, size_t ws_size,
                              hipStream_t stream) {
    const float* feats = (const float*)d_in[0];   // (1, T, L) fp32
    const float* trans = (const float*)d_in[1];   // (L, L) fp32
    float* out = (float*)d_out;                   // [score, path(T) as float]
    char* ws = (char*)d_ws;
    float* ckpt = (float*)(ws + CKPT_OFF);
    unsigned char* M = (unsigned char*)(ws + M_OFF);
    int* etag = (int*)(ws + ETAG_OFF);

    hipLaunchKernelGGL(k_forward, dim3(1), dim3(256), 0, stream, feats, trans, ckpt);
    hipLaunchKernelGGL(k_maps, dim3(NCH), dim3(64), 0, stream, feats, trans, ckpt, M);
    hipLaunchKernelGGL(k_stitch, dim3(1), dim3(64), 0, stream, trans, ckpt, M, etag, out);
    hipLaunchKernelGGL(k_emit, dim3(NCH), dim3(64), 0, stream, feats, trans, ckpt, etag, out);
}

// Round 8
// 35324.576 us; speedup vs baseline: 1.2228x; 1.2228x over previous
//
#include <hip/hip_runtime.h>

#define L 64
#define TLEN 200000
#define CH 528                        // divisible by 8; checkpoint cadence
#define NCH 379                       // ceil(200000/528); 378*528 = 199584
#define LASTLEN (TLEN - (NCH - 1) * CH)   // 416 (divisible by 8)
#define NEGV -10000.0f
#define STARTT 62
#define STOPT 63

// workspace layout (bytes) — total 123052 < 126940 proven available
#define CKPT_OFF 0                          // float[(NCH+1)*L]  = 97280 B
#define M_OFF ((NCH + 1) * L * 4)           // uchar[NCH*L]      = 24256 B
#define ETAG_OFF (M_OFF + NCH * L)          // int[NCH]          = 1516 B

typedef float f32x4 __attribute__((ext_vector_type(4)));

// Drained barrier: init only (plain ds_writes must be globally visible).
#define WAVE_BARRIER() __asm__ volatile("s_waitcnt lgkmcnt(0)\ns_barrier" ::: "memory")
// Per-step barrier WITHOUT lgkmcnt drain — validated rounds 3-6 (absmax 0,
// incl. the plain-write variants R4/R6): pre-barrier LDS ops are serviced
// before post-barrier ops reach the pipe.
#define FAST_BARRIER() __asm__ volatile("s_barrier" ::: "memory")
#define STEP_BARRIER() __asm__ volatile("" ::: "memory")

// force v_max3_f32 (3-input max, 1 instruction); max is order-invariant over
// finite floats so every tree below is bit-identical to pairwise fmax.
__device__ __forceinline__ float max3f(float a, float b, float c) {
    float r;
    __asm__("v_max3_f32 %0, %1, %2, %3" : "=v"(r) : "v"(a), "v"(b), "v"(c));
    return r;
}

// DPP quad_perm butterfly (lane-crossing within a 4-lane quad only):
// 0xB1 = [1,0,3,2] (xor 1), 0x4E = [2,3,0,1] (xor 2).
#define QPERM(x, ctrl)                                                         \
    __int_as_float(__builtin_amdgcn_update_dpp(                                \
        __float_as_int(x), __float_as_int(x), ctrl, 0xf, 0xf, false))

// ---------------------------------------------------------------------------
// Pass 1: exact sequential forward recurrence (the critical path).
// 4 waves (256 threads), DEST-split with quad-level prev-split:
//   wave w owns dest-tags [16w, 16w+16); lane l = 4*d' + g serves dest
//   d = 16w + d' and prev-group g (prevs [16g, 16g+16)).
// Per step:
//   (1) 4 broadcast ds_read_b128 of the combined vbuf[RD][16g..16g+16)
//       (4 distinct 64B rows x 16-lane broadcast; worst 2-way banks = free).
//   (2) 16 adds vs the 4 pinned T quads + 8-op max3 tree -> quad partial.
//   (3) quad butterfly: 2x (quad_perm DPP + fmax) -> all 4 lanes hold
//       max over all 64 prevs for dest d. ONLY 2 cross-lane ops on the
//       chain (R5/R6 lesson: wide RL/DPP broadcasts cost 100+ cy; the
//       read-side LDS broadcast does the wide fan-out for free).
//   (4) + feat[t][d] (single rounding), predicated plain ds_write_b32 by
//       lane g==0: 16 writers/wave to 16 distinct banks, no RMW, no reset
//       (R3's atomic tail ~140cy is gone), double-buffered; no-drain barrier.
// Bit-exactness: each score is one RN(v[p]+T[d][p]); max over 64 is
// order-invariant; +feat rounded once => checkpoints match the reference
// bit-for-bit; replay kernels unchanged.
// ---------------------------------------------------------------------------
__global__ __launch_bounds__(256, 1) void k_forward(const float* __restrict__ feats,
                                                    const float* __restrict__ trans,
                                                    float* __restrict__ ckpt) {
    const int tid = threadIdx.x;
    const int l = tid & 63;
    const int w = tid >> 6;
    const int d = 16 * w + (l >> 2);   // dest-tag owned by this lane's quad
    const int g = l & 3;               // prev-group handled by this lane
    const bool writer = (g == 0);

    // T[d][16g .. 16g+16) — 4 quads; pin keeps them VGPR-resident (R0-proven
    // budget; R1 showed 16 quads/lane does NOT allocate).
    const f32x4* t4 = reinterpret_cast<const f32x4*>(trans) + d * 16 + g * 4;
    f32x4 q0 = t4[0], q1 = t4[1], q2 = t4[2], q3 = t4[3];
    __asm__ volatile("" : "+v"(q0), "+v"(q1), "+v"(q2), "+v"(q3));

    // combined v, double-buffered; writes: 16 distinct banks/wave (free);
    // reads: 4x b128 broadcast rows, worst 2-way (free).
    __shared__ __align__(16) float vbuf[2][L];

    float vq = (d == STARTT) ? 0.0f : NEGV;  // v_{-1}[d] (all 4 lanes of quad)
    if (writer) vbuf[0][d] = vq;
    WAVE_BARRIER();

    // feat prefetch: feats[t][d] (quad-broadcast address; off the chain)
    float fc[8];
#pragma unroll
    for (int j = 0; j < 8; ++j) fc[j] = feats[j * L + d];

    int nextck = 0, cidx = 0;

#define FWD_STEP(RD, WR, FEAT)                                                 \
    do {                                                                       \
        const f32x4 va0 = *reinterpret_cast<const f32x4*>(&vbuf[RD][16 * g + 0]);  \
        const f32x4 va1 = *reinterpret_cast<const f32x4*>(&vbuf[RD][16 * g + 4]);  \
        const f32x4 va2 = *reinterpret_cast<const f32x4*>(&vbuf[RD][16 * g + 8]);  \
        const f32x4 va3 = *reinterpret_cast<const f32x4*>(&vbuf[RD][16 * g + 12]); \
        const f32x4 s0 = va0 + q0, s1 = va1 + q1, s2 = va2 + q2, s3 = va3 + q3;    \
        const float m0 = max3f(fmaxf(s0.x, s0.y), s0.z, s0.w);                 \
        const float m1 = max3f(fmaxf(s1.x, s1.y), s1.z, s1.w);                 \
        const float m2 = max3f(fmaxf(s2.x, s2.y), s2.z, s2.w);                 \
        const float m3 = max3f(fmaxf(s3.x, s3.y), s3.z, s3.w);                 \
        float x = fmaxf(max3f(m0, m1, m2), m3);                                \
        x = fmaxf(x, QPERM(x, 0xB1));                                          \
        x = fmaxf(x, QPERM(x, 0x4E));                                          \
        vq = x + (FEAT);                                                       \
        if (writer) vbuf[WR][d] = vq;                                          \
        FAST_BARRIER();                                                        \
    } while (0)

    for (int tb = 0; tb < TLEN; tb += 8) {
        if (tb == nextck) {
            // vq holds v_{tb-1}[d] in all 4 quad lanes; writers cover all 64
            if (writer) ckpt[cidx * L + d] = vq;
            nextck += CH;
            ++cidx;
        }
        float fn_[8];
        const bool more = (tb + 8) < TLEN;
        if (more) {
#pragma unroll
            for (int j = 0; j < 8; ++j) fn_[j] = feats[(tb + 8 + j) * L + d];
        }
        FWD_STEP(0, 1, fc[0]);
        FWD_STEP(1, 0, fc[1]);
        FWD_STEP(0, 1, fc[2]);
        FWD_STEP(1, 0, fc[3]);
        FWD_STEP(0, 1, fc[4]);
        FWD_STEP(1, 0, fc[5]);
        FWD_STEP(0, 1, fc[6]);
        FWD_STEP(1, 0, fc[7]);
        if (more) {
#pragma unroll
            for (int j = 0; j < 8; ++j) fc[j] = fn_[j];
        }
    }
    // vq = v_{199999}[d]
    if (writer) ckpt[NCH * L + d] = vq;
#undef FWD_STEP
}

// ---------------------------------------------------------------------------
// helpers for the replay kernels (off the critical path, ~0.8 ms total)
// ---------------------------------------------------------------------------
__device__ __forceinline__ void load_trow(const float* __restrict__ trans, int n, float* trow) {
#pragma unroll
    for (int i = 0; i < 16; ++i) {
        const f32x4 q = reinterpret_cast<const f32x4*>(trans)[n * 16 + i];
        trow[4 * i + 0] = q.x;
        trow[4 * i + 1] = q.y;
        trow[4 * i + 2] = q.z;
        trow[4 * i + 3] = q.w;
    }
}

// Bit-exact chunk replay from checkpoint; records backpointers into LDS.
// Single wave per block; in-order DS pipe makes ds_write->ds_read safe with
// only a compiler barrier. Argmax is an in-order strictly-greater scan =>
// first-max, matching jnp.argmax; v matches k_forward bit-for-bit (max is
// order-invariant, +feat monotone-exact).
__device__ __forceinline__ void replay_chunk(const float* __restrict__ feats,
                                             const float* __restrict__ ckpt,
                                             const float* trow, float* vsh,
                                             unsigned char* bpl, int c, int len, int n) {
    float vreg = ckpt[c * L + n];
    vsh[n] = vreg;
    STEP_BARRIER();
    const int base = c * CH;

    float fc[8];
#pragma unroll
    for (int j = 0; j < 8; ++j) fc[j] = feats[(base + j) * L + n];

    for (int sb = 0; sb < len; sb += 8) {
        float fn_[8];
        const bool more = (sb + 8) < len;
        if (more) {
#pragma unroll
            for (int j = 0; j < 8; ++j) fn_[j] = feats[(base + sb + 8 + j) * L + n];
        }
#pragma unroll
        for (int j = 0; j < 8; ++j) {
            float mc[4];
            int ic[4];
#pragma unroll
            for (int g = 0; g < 4; ++g) {
                float m = -INFINITY;
                int idx = g * 16;
#pragma unroll
                for (int r = 0; r < 4; ++r) {
                    const int pb = g * 16 + r * 4;
                    const f32x4 vv = *reinterpret_cast<const f32x4*>(vsh + pb);
                    const float a = vv.x + trow[pb + 0];
                    const float b = vv.y + trow[pb + 1];
                    const float cc = vv.z + trow[pb + 2];
                    const float d = vv.w + trow[pb + 3];
                    if (a > m)  { m = a;  idx = pb + 0; }
                    if (b > m)  { m = b;  idx = pb + 1; }
                    if (cc > m) { m = cc; idx = pb + 2; }
                    if (d > m)  { m = d;  idx = pb + 3; }
                }
                mc[g] = m;
                ic[g] = idx;
            }
            float m = mc[0];
            int idx = ic[0];
            if (mc[1] > m) { m = mc[1]; idx = ic[1]; }
            if (mc[2] > m) { m = mc[2]; idx = ic[2]; }
            if (mc[3] > m) { m = mc[3]; idx = ic[3]; }

            vreg = m + fc[j];
            bpl[(sb + j) * L + n] = (unsigned char)idx;
            vsh[n] = vreg;
            STEP_BARRIER();
        }
        if (more) {
#pragma unroll
            for (int j = 0; j < 8; ++j) fc[j] = fn_[j];
        }
    }
}

// ---------------------------------------------------------------------------
// Pass 2: per-chunk bit-exact replay -> backpointers -> 64-entry chunk map.
// M[c*64+e] = tag at (c*CH - 1) given tag e at the last step of chunk c.
// ---------------------------------------------------------------------------
__global__ __launch_bounds__(64, 1) void k_maps(const float* __restrict__ feats,
                                                const float* __restrict__ trans,
                                                const float* __restrict__ ckpt,
                                                unsigned char* __restrict__ M) {
    const int c = blockIdx.x;
    const int n = threadIdx.x;
    const int len = (c == NCH - 1) ? LASTLEN : CH;

    __shared__ __align__(16) float vsh[L];
    __shared__ unsigned char bpl[CH * L];

    float trow[L];
    load_trow(trans, n, trow);
    replay_chunk(feats, ckpt, trow, vsh, bpl, c, len, n);
    __syncthreads();

    int tag = n;
    for (int s = len - 1; s >= 0; --s) tag = bpl[s * L + tag];
    M[c * L + n] = (unsigned char)tag;
}

// ---------------------------------------------------------------------------
// Pass 3: terminal argmax (bit-exact score) + back-to-front map composition.
// ---------------------------------------------------------------------------
__global__ __launch_bounds__(64, 1) void k_stitch(const float* __restrict__ trans,
                                                  const float* __restrict__ ckpt,
                                                  const unsigned char* __restrict__ M,
                                                  int* __restrict__ etag,
                                                  float* __restrict__ out) {
    const int n = threadIdx.x;
    __shared__ float tsh[L];
    __shared__ int bsh;
    __shared__ __align__(16) unsigned char msh[NCH * L];

    tsh[n] = ckpt[NCH * L + n] + trans[STOPT * L + n];  // terminal[n]
    __syncthreads();
    if (n == 0) {
        float m = tsh[0];
        int b = 0;
        for (int p = 1; p < L; ++p)
            if (tsh[p] > m) { m = tsh[p]; b = p; }  // first-max, like jnp.argmax
        out[0] = m;   // path_score, bit-exact
        bsh = b;
    }
    __syncthreads();

    for (int i = n; i < (NCH * L) / 4; i += L)
        reinterpret_cast<int*>(msh)[i] = reinterpret_cast<const int*>(M)[i];
    __syncthreads();

    if (n == 0) {
        int carry = bsh;  // tag at t = T-1 = end of chunk NCH-1
        for (int c = NCH - 1; c >= 1; --c) {
            etag[c] = carry;
            carry = msh[c * L + carry];
        }
        etag[0] = carry;
    }
}

// ---------------------------------------------------------------------------
// Pass 4: per-chunk replay again, walk backwards from etag[c], emit path.
// Path written as float32 (harness reads the concatenated output as float).
// ---------------------------------------------------------------------------
__global__ __launch_bounds__(64, 1) void k_emit(const float* __restrict__ feats,
                                                const float* __restrict__ trans,
                                                const float* __restrict__ ckpt,
                                                const int* __restrict__ etag,
                                                float* __restrict__ out) {
    const int c = blockIdx.x;
    const int n = threadIdx.x;
    const int len = (c == NCH - 1) ? LASTLEN : CH;

    __shared__ __align__(16) float vsh[L];
    __shared__ unsigned char bpl[CH * L];
    __shared__ unsigned char plc[CH];

    float trow[L];
    load_trow(trans, n, trow);
    replay_chunk(feats, ckpt, trow, vsh, bpl, c, len, n);
    __syncthreads();

    int tag = etag[c];  // uniform; bpl reads below broadcast (same address)
    for (int s = len - 1; s >= 0; --s) {
        if (n == 0) plc[s] = (unsigned char)tag;
        tag = bpl[s * L + tag];
    }
    __syncthreads();

    for (int i = n; i < len; i += L)
        out[1 + c * CH + i] = (float)plc[i];
}

// ---------------------------------------------------------------------------
extern "C" void kernel_launch(void* const* d_in, const int* in_sizes, int n_in,
                              void* d_out, int out_size, void* d_ws, size_t ws_size,
                              hipStream_t stream) {
    const float* feats = (const float*)d_in[0];   // (1, T, L) fp32
    const float* trans = (const float*)d_in[1];   // (L, L) fp32
    float* out = (float*)d_out;                   // [score, path(T) as float]
    char* ws = (char*)d_ws;
    float* ckpt = (float*)(ws + CKPT_OFF);
    unsigned char* M = (unsigned char*)(ws + M_OFF);
    int* etag = (int*)(ws + ETAG_OFF);

    hipLaunchKernelGGL(k_forward, dim3(1), dim3(256), 0, stream, feats, trans, ckpt);
    hipLaunchKernelGGL(k_maps, dim3(NCH), dim3(64), 0, stream, feats, trans, ckpt, M);
    hipLaunchKernelGGL(k_stitch, dim3(1), dim3(64), 0, stream, trans, ckpt, M, etag, out);
    hipLaunchKernelGGL(k_emit, dim3(NCH), dim3(64), 0, stream, feats, trans, ckpt, etag, out);
}

// Round 9
// 30139.908 us; speedup vs baseline: 1.4331x; 1.1720x over previous
//
#include <hip/hip_runtime.h>

#define L 64
#define TLEN 200000
#define CH 528                        // divisible by 6 (fwd unroll) and 8 (replay unroll)
#define NCH 379                       // ceil(200000/528); 378*528 = 199584
#define LASTLEN (TLEN - (NCH - 1) * CH)   // 416 (divisible by 8)
#define MAINT 199992                  // 6*33332, main-loop trip; tail = 8 steps
#define NEGV -10000.0f
#define STARTT 62
#define STOPT 63

// workspace layout (bytes) — total 123052 < 126940 proven available
#define CKPT_OFF 0                          // float[(NCH+1)*L]  = 97280 B
#define M_OFF ((NCH + 1) * L * 4)           // uchar[NCH*L]      = 24256 B
#define ETAG_OFF (M_OFF + NCH * L)          // int[NCH]          = 1516 B

typedef float f32x4 __attribute__((ext_vector_type(4)));

// Drained barrier: init only (plain ds_writes must be globally visible).
#define WAVE_BARRIER() __asm__ volatile("s_waitcnt lgkmcnt(0)\ns_barrier" ::: "memory")
// Per-step barrier WITHOUT lgkmcnt drain — validated rounds 3-8 (absmax 0,
// atomic and plain-write variants): pre-barrier LDS ops are serviced before
// post-barrier LDS ops reach the pipe.
#define FAST_BARRIER() __asm__ volatile("s_barrier" ::: "memory")
#define STEP_BARRIER() __asm__ volatile("" ::: "memory")

// force v_max3_f32 (3-input max, 1 instruction); max is order-invariant over
// finite floats so every tree below is bit-identical to pairwise fmax.
__device__ __forceinline__ float max3f(float a, float b, float c) {
    float r;
    __asm__("v_max3_f32 %0, %1, %2, %3" : "=v"(r) : "v"(a), "v"(b), "v"(c));
    return r;
}

// ---------------------------------------------------------------------------
// Pass 1: exact sequential forward recurrence (the critical path).
// EIGHT waves (512 threads), p-split: wave w owns prev-tags [8w, 8w+8).
// Step model calibrated over R3..R8: period = [s_barrier + ds_read latency
// ~255cy fixed] + on-chain VALU. R3 (4-wave, 16 prevs/lane) had ~92 VALU-cy;
// this variant minimizes on-chain VALU (~35cy: 2 ds_read_b128, 8 adds, 5-op
// max3 tree, 1 feat add, 1 ds_max) and probes whether s_barrier cost scales
// with wave count (8 waves = 2/SIMD).
// Structure is R3's proven skeleton: triple-buffered v, ds_max atomic
// combine, no-drain per-step barrier. Step s reads buf s%3, atomics into
// (s+1)%3, wave0 resets (s+2)%3 (reset issued after the atomic: still
// pre-barrier, so it is ordered before next step's atomics by the validated
// no-drain property; RS != RD so this step's reads are unaffected).
// Bit-exactness: each score is one RN(v[p]+T[n][p]); max (incl. ds_max
// combine) is order-invariant over finite floats; +feat is applied to the
// per-wave partial max BEFORE the atomic — exact because RN is monotone:
// max_w RN(pm_w + f) == RN((max_w pm_w) + f). Checkpoints match the
// reference bit-for-bit; replay kernels unchanged.
// ---------------------------------------------------------------------------
__global__ __launch_bounds__(512, 1) void k_forward(const float* __restrict__ feats,
                                                    const float* __restrict__ trans,
                                                    float* __restrict__ ckpt) {
    const int tid = threadIdx.x;
    const int n = tid & 63;   // next-tag owned by this lane
    const int w = tid >> 6;   // wave id = prev-slice (0..7)

    // T[n][8w .. 8w+8) — 8 floats, 2 quads; pin keeps them VGPR-resident
    // (R0-proven pattern at 4 quads; 2 is comfortably within budget).
    const f32x4* t4 = reinterpret_cast<const f32x4*>(trans) + n * 16 + w * 2;
    f32x4 q0 = t4[0], q1 = t4[1];
    __asm__ volatile("" : "+v"(q0), "+v"(q1));

    __shared__ __align__(16) float vbuf[3][L];

    vbuf[0][n] = (n == STARTT) ? 0.0f : NEGV;  // v_{-1}; same value from all waves
    vbuf[1][n] = -INFINITY;                    // receives step-0 atomics
    vbuf[2][n] = -INFINITY;
    WAVE_BARRIER();

    float fc[6];
#pragma unroll
    for (int j = 0; j < 6; ++j) fc[j] = feats[j * L + n];

    int nextck = 0, cidx = 0;

#define FWD_STEP(RD, WR, RS, FEAT)                                            \
    do {                                                                      \
        const f32x4 va0 = *reinterpret_cast<const f32x4*>(&vbuf[RD][8 * w + 0]); \
        const f32x4 va1 = *reinterpret_cast<const f32x4*>(&vbuf[RD][8 * w + 4]); \
        const f32x4 s0 = va0 + q0, s1 = va1 + q1;                             \
        const float m0 = max3f(fmaxf(s0.x, s0.y), s0.z, s0.w);                \
        const float m1 = max3f(fmaxf(s1.x, s1.y), s1.z, s1.w);                \
        const float cand = fmaxf(m0, m1) + (FEAT);                            \
        __hip_atomic_fetch_max(&vbuf[WR][n], cand, __ATOMIC_RELAXED,          \
                               __HIP_MEMORY_SCOPE_WORKGROUP);                 \
        if (w == 0) vbuf[RS][n] = -INFINITY;                                  \
        FAST_BARRIER();                                                       \
    } while (0)

    for (int tb = 0; tb < MAINT; tb += 6) {
        if (tb == nextck) {
            // vbuf[0] holds v_{tb-1} (tb%3==0 always; 528%6==0 keeps hits aligned)
            if (w == 0) ckpt[cidx * L + n] = vbuf[0][n];
            nextck += CH;
            ++cidx;
        }
        float fn_[6];
        const bool more = (tb + 6) < MAINT;
        if (more) {
#pragma unroll
            for (int j = 0; j < 6; ++j) fn_[j] = feats[(tb + 6 + j) * L + n];
        }
        FWD_STEP(0, 1, 2, fc[0]);
        FWD_STEP(1, 2, 0, fc[1]);
        FWD_STEP(2, 0, 1, fc[2]);
        FWD_STEP(0, 1, 2, fc[3]);
        FWD_STEP(1, 2, 0, fc[4]);
        FWD_STEP(2, 0, 1, fc[5]);
        if (more) {
#pragma unroll
            for (int j = 0; j < 6; ++j) fc[j] = fn_[j];
        }
    }

    // tail: steps 199992..199999 (MAINT%3==0, so the rotation continues)
    float ft[8];
#pragma unroll
    for (int j = 0; j < 8; ++j) ft[j] = feats[(MAINT + j) * L + n];
    FWD_STEP(0, 1, 2, ft[0]);
    FWD_STEP(1, 2, 0, ft[1]);
    FWD_STEP(2, 0, 1, ft[2]);
    FWD_STEP(0, 1, 2, ft[3]);
    FWD_STEP(1, 2, 0, ft[4]);
    FWD_STEP(2, 0, 1, ft[5]);
    FWD_STEP(0, 1, 2, ft[6]);
    FWD_STEP(1, 2, 0, ft[7]);
    // v_{199999} lives in vbuf[200000 % 3] = vbuf[2]
    if (w == 0) ckpt[NCH * L + n] = vbuf[2][n];
#undef FWD_STEP
}

// ---------------------------------------------------------------------------
// helpers for the replay kernels (off the critical path, ~0.8 ms total)
// ---------------------------------------------------------------------------
__device__ __forceinline__ void load_trow(const float* __restrict__ trans, int n, float* trow) {
#pragma unroll
    for (int i = 0; i < 16; ++i) {
        const f32x4 q = reinterpret_cast<const f32x4*>(trans)[n * 16 + i];
        trow[4 * i + 0] = q.x;
        trow[4 * i + 1] = q.y;
        trow[4 * i + 2] = q.z;
        trow[4 * i + 3] = q.w;
    }
}

// Bit-exact chunk replay from checkpoint; records backpointers into LDS.
// Single wave per block; in-order DS pipe makes ds_write->ds_read safe with
// only a compiler barrier. Argmax is an in-order strictly-greater scan =>
// first-max, matching jnp.argmax; v matches k_forward bit-for-bit (max is
// order-invariant, +feat monotone-exact).
__device__ __forceinline__ void replay_chunk(const float* __restrict__ feats,
                                             const float* __restrict__ ckpt,
                                             const float* trow, float* vsh,
                                             unsigned char* bpl, int c, int len, int n) {
    float vreg = ckpt[c * L + n];
    vsh[n] = vreg;
    STEP_BARRIER();
    const int base = c * CH;

    float fc[8];
#pragma unroll
    for (int j = 0; j < 8; ++j) fc[j] = feats[(base + j) * L + n];

    for (int sb = 0; sb < len; sb += 8) {
        float fn_[8];
        const bool more = (sb + 8) < len;
        if (more) {
#pragma unroll
            for (int j = 0; j < 8; ++j) fn_[j] = feats[(base + sb + 8 + j) * L + n];
        }
#pragma unroll
        for (int j = 0; j < 8; ++j) {
            float mc[4];
            int ic[4];
#pragma unroll
            for (int g = 0; g < 4; ++g) {
                float m = -INFINITY;
                int idx = g * 16;
#pragma unroll
                for (int r = 0; r < 4; ++r) {
                    const int pb = g * 16 + r * 4;
                    const f32x4 vv = *reinterpret_cast<const f32x4*>(vsh + pb);
                    const float a = vv.x + trow[pb + 0];
                    const float b = vv.y + trow[pb + 1];
                    const float cc = vv.z + trow[pb + 2];
                    const float d = vv.w + trow[pb + 3];
                    if (a > m)  { m = a;  idx = pb + 0; }
                    if (b > m)  { m = b;  idx = pb + 1; }
                    if (cc > m) { m = cc; idx = pb + 2; }
                    if (d > m)  { m = d;  idx = pb + 3; }
                }
                mc[g] = m;
                ic[g] = idx;
            }
            float m = mc[0];
            int idx = ic[0];
            if (mc[1] > m) { m = mc[1]; idx = ic[1]; }
            if (mc[2] > m) { m = mc[2]; idx = ic[2]; }
            if (mc[3] > m) { m = mc[3]; idx = ic[3]; }

            vreg = m + fc[j];
            bpl[(sb + j) * L + n] = (unsigned char)idx;
            vsh[n] = vreg;
            STEP_BARRIER();
        }
        if (more) {
#pragma unroll
            for (int j = 0; j < 8; ++j) fc[j] = fn_[j];
        }
    }
}

// ---------------------------------------------------------------------------
// Pass 2: per-chunk bit-exact replay -> backpointers -> 64-entry chunk map.
// M[c*64+e] = tag at (c*CH - 1) given tag e at the last step of chunk c.
// ---------------------------------------------------------------------------
__global__ __launch_bounds__(64, 1) void k_maps(const float* __restrict__ feats,
                                                const float* __restrict__ trans,
                                                const float* __restrict__ ckpt,
                                                unsigned char* __restrict__ M) {
    const int c = blockIdx.x;
    const int n = threadIdx.x;
    const int len = (c == NCH - 1) ? LASTLEN : CH;

    __shared__ __align__(16) float vsh[L];
    __shared__ unsigned char bpl[CH * L];

    float trow[L];
    load_trow(trans, n, trow);
    replay_chunk(feats, ckpt, trow, vsh, bpl, c, len, n);
    __syncthreads();

    int tag = n;
    for (int s = len - 1; s >= 0; --s) tag = bpl[s * L + tag];
    M[c * L + n] = (unsigned char)tag;
}

// ---------------------------------------------------------------------------
// Pass 3: terminal argmax (bit-exact score) + back-to-front map composition.
// ---------------------------------------------------------------------------
__global__ __launch_bounds__(64, 1) void k_stitch(const float* __restrict__ trans,
                                                  const float* __restrict__ ckpt,
                                                  const unsigned char* __restrict__ M,
                                                  int* __restrict__ etag,
                                                  float* __restrict__ out) {
    const int n = threadIdx.x;
    __shared__ float tsh[L];
    __shared__ int bsh;
    __shared__ __align__(16) unsigned char msh[NCH * L];

    tsh[n] = ckpt[NCH * L + n] + trans[STOPT * L + n];  // terminal[n]
    __syncthreads();
    if (n == 0) {
        float m = tsh[0];
        int b = 0;
        for (int p = 1; p < L; ++p)
            if (tsh[p] > m) { m = tsh[p]; b = p; }  // first-max, like jnp.argmax
        out[0] = m;   // path_score, bit-exact
        bsh = b;
    }
    __syncthreads();

    for (int i = n; i < (NCH * L) / 4; i += L)
        reinterpret_cast<int*>(msh)[i] = reinterpret_cast<const int*>(M)[i];
    __syncthreads();

    if (n == 0) {
        int carry = bsh;  // tag at t = T-1 = end of chunk NCH-1
        for (int c = NCH - 1; c >= 1; --c) {
            etag[c] = carry;
            carry = msh[c * L + carry];
        }
        etag[0] = carry;
    }
}

// ---------------------------------------------------------------------------
// Pass 4: per-chunk replay again, walk backwards from etag[c], emit path.
// Path written as float32 (harness reads the concatenated output as float).
// ---------------------------------------------------------------------------
__global__ __launch_bounds__(64, 1) void k_emit(const float* __restrict__ feats,
                                                const float* __restrict__ trans,
                                                const float* __restrict__ ckpt,
                                                const int* __restrict__ etag,
                                                float* __restrict__ out) {
    const int c = blockIdx.x;
    const int n = threadIdx.x;
    const int len = (c == NCH - 1) ? LASTLEN : CH;

    __shared__ __align__(16) float vsh[L];
    __shared__ unsigned char bpl[CH * L];
    __shared__ unsigned char plc[CH];

    float trow[L];
    load_trow(trans, n, trow);
    replay_chunk(feats, ckpt, trow, vsh, bpl, c, len, n);
    __syncthreads();

    int tag = etag[c];  // uniform; bpl reads below broadcast (same address)
    for (int s = len - 1; s >= 0; --s) {
        if (n == 0) plc[s] = (unsigned char)tag;
        tag = bpl[s * L + tag];
    }
    __syncthreads();

    for (int i = n; i < len; i += L)
        out[1 + c * CH + i] = (float)plc[i];
}

// ---------------------------------------------------------------------------
extern "C" void kernel_launch(void* const* d_in, const int* in_sizes, int n_in,
                              void* d_out, int out_size, void* d_ws, size_t ws_size,
                              hipStream_t stream) {
    const float* feats = (const float*)d_in[0];   // (1, T, L) fp32
    const float* trans = (const float*)d_in[1];   // (L, L) fp32
    float* out = (float*)d_out;                   // [score, path(T) as float]
    char* ws = (char*)d_ws;
    float* ckpt = (float*)(ws + CKPT_OFF);
    unsigned char* M = (unsigned char*)(ws + M_OFF);
    int* etag = (int*)(ws + ETAG_OFF);

    hipLaunchKernelGGL(k_forward, dim3(1), dim3(512), 0, stream, feats, trans, ckpt);
    hipLaunchKernelGGL(k_maps, dim3(NCH), dim3(64), 0, stream, feats, trans, ckpt, M);
    hipLaunchKernelGGL(k_stitch, dim3(1), dim3(64), 0, stream, trans, ckpt, M, etag, out);
    hipLaunchKernelGGL(k_emit, dim3(NCH), dim3(64), 0, stream, feats, trans, ckpt, etag, out);
}